// Round 1
// 62.027 us; speedup vs baseline: 1.0012x; 1.0012x over previous
//
#include <hip/hip_runtime.h>
#include <stdint.h>

// DTM layer: B=4, C=3, H=W=64. Unit lattice => dist^2 = di^2 + dj^2.
// Per pixel: walk lattice offsets in increasing d2, accumulate weight until
// crossing bound = 0.05*sum(w); val = cumd_before + d2*(bound - cum_before).
// EXACTNESS: (1) equal-d2 shells are order- and grouping-invariant, so we
// walk symmetry GROUPS {(+-d,+-e)} via wpair[d][j] = w[pi-d][j] + w[pi+d][j]
// (zero-haloed; 2 validity-free LDS gathers per group); (2) the reference's
// max_k clip never binds; (3) any crossing beyond the speculative window is
// resolved by an exact global-memory fallback walk.
//
// Round-8: ADAPTIVE WINDOW (per-row nc[pi]/dmax[pi] tables, NEED=260).
// Round-9: LATENCY PASS. The harness's 268MB workspace poison fill flushes
// L2+L3 every iteration, so all first-touch global reads are ~900cy HBM
// misses. (a) window meta (320x8B) is now staged to LDS once per block and
// phase A/B read it from LDS instead of cold global (phase B's 20 per-lane
// meta loads were serialized on wave0's critical path); (b) phase-B chunk
// summaries are preloaded into registers so the 15 ds_read_b64 batch instead
// of serializing through the select chain; (c) launch_bounds 8->6 waves/EU:
// grid is 768 blocks = 3 blocks/CU, so 6 waves/EU already gives full
// residency and the VGPR cap rises 64->84 (kills any phase-B spills).

#define HW     4096
#define NBIN   8192
#define WIN_D2 360
#define HSTR   100         // wpair row stride = 64 + 2*18
#define HOFF   18
#define WROWS  19          // d = 0..18
#define WPN    (WROWS * HSTR)
#define NCHUNK 16
#define NG     4096        // all (d,e) in [0,64)^2 groups
#define NEED   260         // worst-lane effective entries to cover crossing

struct alignas(8) GM { uint32_t de; float d2; };  // de = d | e<<6 | code<<12; code:0->sc1,1->sc0.5,2->sc0

constexpr int cnt_win_groups() {
    int n = 0;
    for (int d = 0; d < 64; ++d)
        for (int e = 0; e < 64; ++e)
            if (d * d + e * e <= WIN_D2) ++n;
    return n;
}
constexpr int NWIN  = cnt_win_groups();              // 316
constexpr int GPC   = 20;
constexpr int NWINP = GPC * NCHUNK;                  // 320

struct GTabs { GM g[NG]; GM w[NWINP]; int nc[64]; int dmax[64]; };

constexpr GTabs make_tabs() {
    GTabs t{};
    int cnt[NBIN] = {};
    for (int d = 0; d < 64; ++d)
        for (int e = 0; e < 64; ++e) cnt[d * d + e * e]++;
    int run = 0;
    for (int b = 0; b < NBIN; ++b) { int c = cnt[b]; cnt[b] = run; run += c; }
    for (int d = 0; d < 64; ++d)
        for (int e = 0; e < 64; ++e) {
            int d2 = d * d + e * e;
            int pos = cnt[d2]++;
            unsigned code = (e == 0) ? 1u : 0u;  // e==0: same addr twice -> 0.5
            t.g[pos].de = (uint32_t)d | ((uint32_t)e << 6) | (code << 12);
            t.g[pos].d2 = (float)d2;
        }
    for (int i = 0; i < NWIN; ++i) t.w[i] = t.g[i];
    for (int i = NWIN; i < NWINP; ++i) { t.w[i].de = (2u << 12); t.w[i].d2 = (float)WIN_D2; }
    // per-row chunk count: simulate worst lane (col 0) cumulative entry yield
    for (int pi = 0; pi < 64; ++pi) {
        int md = pi < 63 - pi ? pi : 63 - pi;   // row margin
        int y = 0, G = 0;
        while (y < NEED && G < NWIN) {
            int d = (int)(t.g[G].de & 63u);
            y += (d == 0) ? 1 : ((d <= md) ? 2 : 1);
            ++G;
        }
        int nc = (G + GPC - 1) / GPC;
        if (nc < 1) nc = 1;
        t.nc[pi] = nc;
        int dm = 0;
        for (int i = 0; i < nc * GPC && i < NWIN; ++i) {
            int d = (int)(t.g[i].de & 63u);
            if (d > dm) dm = d;
        }
        t.dmax[pi] = dm;
    }
    return t;
}
__device__ const GTabs g_t = make_tabs();

constexpr int max_nc() {
    GTabs t = make_tabs();
    int m = 0;
    for (int i = 0; i < 64; ++i) if (t.nc[i] > m) m = t.nc[i];
    return m;
}
static_assert(max_nc() * GPC <= NWIN, "window table must cover worst row");

__global__ __launch_bounds__(512, 6) void dtm_kernel(const float* __restrict__ x,
                                                     float* __restrict__ out) {
    __shared__ float  wpair[WPN];          // 7.6 KB
    __shared__ float2 summ[NCHUNK][64];    // 8 KB
    __shared__ uint2  wmeta[NWINP];        // 2.5 KB window meta (LDS-resident)
    __shared__ float  red[8];

    int bc   = blockIdx.x >> 6;
    int pi   = blockIdx.x & 63;   // row (uniform)
    int tid  = threadIdx.x;       // 0..511
    int lane = tid & 63;          // pixel column
    int wv   = tid >> 6;          // wave 0..7

    const float* __restrict__ xs = x + (size_t)bc * HW;
    int nc  = __builtin_amdgcn_readfirstlane(g_t.nc[pi]);
    int dmx = __builtin_amdgcn_readfirstlane(g_t.dmax[pi]);

    // ---- stage window meta to LDS (one coalesced 8B load per thread) ----
    if (tid < NWINP)
        wmeta[tid] = reinterpret_cast<const uint2*>(g_t.w)[tid];

    // ---- bound: direct global float4 reduce (2 per thread) ----
    const float4* xb = (const float4*)xs;
    float4 a0 = xb[tid];
    float4 a1 = xb[tid + 512];
    float s = ((a0.x + a0.y) + (a0.z + a0.w)) + ((a1.x + a1.y) + (a1.z + a1.w));
    #pragma unroll
    for (int off = 32; off >= 1; off >>= 1) s += __shfl_down(s, off, 64);
    if (lane == 0) red[wv] = s;

    // ---- build zero-haloed wpair rows 0..dmx, branchless (loads batch) ----
    int wlen = (dmx + 1) * HSTR;
    for (int idx = tid; idx < wlen; idx += 512) {
        int d = idx / HSTR;
        int c = idx - d * HSTR;
        int j = c - HOFF;                    // -18..81
        bool jv = (unsigned)j < 64u;
        int ja = jv ? j : 0;
        int rm = pi - d, rp = pi + d;
        float vm = xs[(rm > 0 ? rm : 0) * 64 + ja];
        float vp = xs[(rp < 63 ? rp : 63) * 64 + ja];
        float v = (rm >= 0 ? vm : 0.f) + ((d > 0 && rp < 64) ? vp : 0.f);
        wpair[idx] = jv ? v : 0.f;
    }
    __syncthreads();

    // meta for this wave's (up to) two chunks, reg-resident from LDS
    int li = lane < GPC ? lane : GPC - 1;
    uint2 mv0 = wmeta[wv * GPC + li];
    uint2 mv1 = wmeta[(wv + 8) * GPC + li];

    // ---- phase A: chunk partials (mass, d2*mass) per pixel ----
    #pragma unroll
    for (int h = 0; h < 2; ++h) {
        int chunk = wv + 8 * h;
        if (chunk < nc) {                    // wave-uniform, per-chunk branch
            uint2 mv = h ? mv1 : mv0;
            float m0 = 0.f, dm0 = 0.f;
            #pragma unroll 5
            for (int k = 0; k < GPC; ++k) {
                uint32_t de = (uint32_t)__builtin_amdgcn_readlane((int)mv.x, k);
                float d2 = __uint_as_float(
                    (uint32_t)__builtin_amdgcn_readlane((int)mv.y, k));
                int d = de & 63, e = (de >> 6) & 63;
                unsigned code = de >> 12;
                float sc = code == 0 ? 1.f : (code == 1 ? 0.5f : 0.f);
                int base = d * HSTR + HOFF;                  // scalar
                float g1 = wpair[base + lane - e];
                float g2 = wpair[base + lane + e];
                float m = sc * (g1 + g2);
                m0 += m;
                dm0 = fmaf(d2, m, dm0);
            }
            summ[chunk][lane] = make_float2(m0, dm0);
        }
    }
    __syncthreads();
    if (wv != 0) return;

    // ---- phase B (wave 0): per-lane pixel = column lane of row pi ----
    float bound = 0.f;
    #pragma unroll
    for (int i = 0; i < 8; ++i) bound += red[i];
    bound *= 0.05f;

    // preload chunk summaries (uniform guards; loads batch, no chain dep)
    float2 pch[NCHUNK - 1];
    #pragma unroll
    for (int c = 0; c < NCHUNK - 1; ++c)
        if (c < nc - 1) pch[c] = summ[c][lane];

    float rem = bound, cumd = 0.f;
    int cstar = nc - 1;
    bool found = false;
    #pragma unroll
    for (int c = 0; c < NCHUNK - 1; ++c) {
        if (c < nc - 1) {                    // uniform predicate
            float2 p = pch[c];
            bool cross = (!found) && (p.x >= rem);
            cstar = cross ? c : cstar;
            bool adv = (!found) && (!cross);
            rem   = adv ? rem - p.x : rem;
            cumd  = adv ? cumd + p.y : cumd;
            found = found || cross;
        }
    }

    // walk the 20 groups of the crossing chunk (meta from LDS)
    float val = 0.f;
    bool done = false;
    int g0 = cstar * GPC;
    #pragma unroll 4
    for (int k = 0; k < GPC; ++k) {
        uint2 mm = wmeta[g0 + k];
        int d = mm.x & 63, e = (mm.x >> 6) & 63;
        unsigned code = mm.x >> 12;
        float d2 = __uint_as_float(mm.y);
        float sc = code == 0 ? 1.f : (code == 1 ? 0.5f : 0.f);
        int base = d * HSTR + HOFF + lane;
        float m = sc * (wpair[base - e] + wpair[base + e]);
        float wq = done ? 0.f : m;
        bool cross = (!done) && (wq >= rem);
        val  = cross ? fmaf(d2, rem, cumd) : val;
        done = done || cross;
        cumd = fmaf(d2, wq, cumd);
        rem -= wq;
    }

    // exact fallback beyond the walked chunk (ulp boundary cases or crossing
    // past the adaptive window); practically never iterates
    int pos = g0 + GPC; if (pos > NWIN) pos = NWIN;
    const GM* __restrict__ mg = g_t.g;
    while (__any(!done)) {
        int ix = pos < NG ? pos : NG - 1;
        GM mm = mg[ix];
        int d = mm.de & 63, e = (mm.de >> 6) & 63;
        float sc = ((mm.de >> 12) == 1u) ? 0.5f : 1.f;
        if (d == 0) sc *= 0.5f;
        int rm = pi - d, rp = pi + d;
        int cm = lane - e, cp = lane + e;
        float m = 0.f;
        if (rm >= 0 && cm >= 0) m += xs[rm * 64 + cm];
        if (rm >= 0 && cp < 64) m += xs[rm * 64 + cp];
        if (rp < 64 && cm >= 0) m += xs[rp * 64 + cm];
        if (rp < 64 && cp < 64) m += xs[rp * 64 + cp];
        m *= sc;
        float wq = done ? 0.f : m;
        bool cross = (!done) && ((wq >= rem) || (pos >= NG));
        val  = cross ? fmaf(mm.d2, rem, cumd) : val;
        done = done || cross;
        cumd = fmaf(mm.d2, wq, cumd);
        rem -= wq;
        pos++;
    }

    out[(size_t)bc * HW + (pi << 6) + lane] = sqrtf(val / bound);
}

extern "C" void kernel_launch(void* const* d_in, const int* in_sizes, int n_in,
                              void* d_out, int out_size, void* d_ws, size_t ws_size,
                              hipStream_t stream) {
    const float* x = (const float*)d_in[0];
    float* out = (float*)d_out;
    int BC = in_sizes[0] / HW;   // 12 for (4,3,64,64)
    dtm_kernel<<<BC * 64, 512, 0, stream>>>(x, out);
}